// Round 8
// baseline (55.442 us; speedup 1.0000x reference)
//
#include <hip/hip_runtime.h>

#define NCLS  19
#define NBINS 15
#define HW    (512 * 512)        // 262144
#define NPIX  (8 * HW)           // 2097152
#define BLOCKS_PER_IMG (HW / 256)  // 1024

// exp(x) for x in ~[-7, 7]; rel err ~7e-12 (degree-9 exp2 Taylor).
// Bin decisions need ~1e-10 rel accuracy vs the f64 numpy reference -> ok.
__device__ __forceinline__ double dexp_fast(double x) {
    const double LOG2E = 1.4426950408889634074;
    double t = x * LOG2E;
    double n = rint(t);                 // v_rndne_f64
    double r = t - n;                   // exact, r in [-0.5, 0.5]
    double p;
    p =                  1.0178086009239699e-07;      // ln2^9/9!
    p = __builtin_fma(p, r, 1.3215486790144309e-06);  // ln2^8/8!
    p = __builtin_fma(p, r, 1.5252733804059840e-05);  // ln2^7/7!
    p = __builtin_fma(p, r, 1.5403530393381609e-04);  // ln2^6/6!
    p = __builtin_fma(p, r, 1.3333558146428443e-03);  // ln2^5/5!
    p = __builtin_fma(p, r, 9.6181291076284772e-03);  // ln2^4/4!
    p = __builtin_fma(p, r, 5.5504108664821580e-02);  // ln2^3/3!
    p = __builtin_fma(p, r, 2.4022650695910071e-01);  // ln2^2/2!
    p = __builtin_fma(p, r, 6.9314718055994531e-01);  // ln2
    p = __builtin_fma(p, r, 1.0);
    int ni = (int)n;
    long long bits = ((long long)(ni + 1023)) << 52;
    return p * __longlong_as_double(bits);
}

typedef const void __attribute__((address_space(1)))* as1_cptr;
typedef void       __attribute__((address_space(3)))* as3_ptr;

__global__ void __launch_bounds__(256)
histcal_kernel(const float* __restrict__ logits,
               const float* __restrict__ val_freqs,
               float* __restrict__ out)
{
    __shared__ float tile[NCLS][256];   // 19.0 KB staged logits tile
    __shared__ float svf[NCLS * NBINS]; // 1.1 KB calibration table

    for (int t = threadIdx.x; t < NCLS * NBINS; t += 256)
        svf[t] = val_freqs[t];

    unsigned b   = blockIdx.x >> 10;                  // image index
    unsigned hw0 = (blockIdx.x & (BLOCKS_PER_IMG - 1)) << 8;
    size_t imgbase = (size_t)b * ((size_t)NCLS * HW) + hw0;
    const float* gbase = logits + imgbase;
    float*       op    = out + imgbase + threadIdx.x;

    // Stage the whole 19x256 tile straight to LDS: each wave issues ~5
    // global_load_lds (16B/lane, 1KB/wave-instr = one full plane row each).
    int wave = threadIdx.x >> 6;
    int lane = threadIdx.x & 63;
    for (int c = wave; c < NCLS; c += 4) {
        const float* gsrc = gbase + (size_t)c * HW + (lane << 2);
        __builtin_amdgcn_global_load_lds((as1_cptr)gsrc, (as3_ptr)&tile[c][0],
                                         16, 0, 0);
    }
    __syncthreads();   // drains vmcnt: tile + svf ready

    int t = threadIdx.x;

    // Pass 1: exp + sum from LDS (consecutive lanes -> consecutive banks).
    double s = 0.0;
    #pragma unroll
    for (int c = 0; c < NCLS; ++c)
        s += dexp_fast((double)tile[c][t]);
    double sc = 15.0 / s;

    // Pass 2: recompute exp (proven hidden), bin in f64, gather, class-sum.
    float cal[NCLS];
    float tt = 0.f;
    #pragma unroll
    for (int c = 0; c < NCLS; ++c) {
        int bi = (int)(dexp_fast((double)tile[c][t]) * sc);  // >=0, trunc==floor
        bi = bi > NBINS - 1 ? NBINS - 1 : bi;
        float v = svf[c * NBINS + bi];
        cal[c] = v;
        tt += v;
    }
    if (tt == 0.f) tt = 1.f;
    float inv = 1.f / tt;

    // Pass 3: streaming write-out (stores don't stall the wave).
    #pragma unroll
    for (int c = 0; c < NCLS; ++c)
        __builtin_nontemporal_store(cal[c] * inv, op + (size_t)c * HW);
}

extern "C" void kernel_launch(void* const* d_in, const int* in_sizes, int n_in,
                              void* d_out, int out_size, void* d_ws, size_t ws_size,
                              hipStream_t stream) {
    const float* logits    = (const float*)d_in[0];   // [8,19,512,512] f32
    const float* val_freqs = (const float*)d_in[1];   // [19,15] f32
    float* out = (float*)d_out;                       // [8,19,512,512] f32
    histcal_kernel<<<dim3(NPIX / 256), dim3(256), 0, stream>>>(logits, val_freqs, out);
}

// Round 9
// 53.752 us; speedup vs baseline: 1.0314x; 1.0314x over previous
//
#include <hip/hip_runtime.h>

#define NCLS  19
#define NBINS 15
#define HW    (512 * 512)        // 262144
#define NPIX  (8 * HW)           // 2097152

// Near-boundary threshold for the f32 fast path. Worst-case f32 abs error on
// p15 at boundary k is ~k*1.6e-6 <= 2.2e-5 (k<=14); 7e-5 gives >=3x margin.
#define EPS 7e-5f

// exp(x) for x in ~[-7, 7]; rel err ~7e-12 (degree-9 exp2 Taylor).
// The fallback path: bin decisions match an f64 numpy reference.
__device__ __forceinline__ double dexp_fast(double x) {
    const double LOG2E = 1.4426950408889634074;
    double t = x * LOG2E;
    double n = rint(t);                 // v_rndne_f64
    double r = t - n;                   // exact, r in [-0.5, 0.5]
    double p;
    p =                  1.0178086009239699e-07;      // ln2^9/9!
    p = __builtin_fma(p, r, 1.3215486790144309e-06);  // ln2^8/8!
    p = __builtin_fma(p, r, 1.5252733804059840e-05);  // ln2^7/7!
    p = __builtin_fma(p, r, 1.5403530393381609e-04);  // ln2^6/6!
    p = __builtin_fma(p, r, 1.3333558146428443e-03);  // ln2^5/5!
    p = __builtin_fma(p, r, 9.6181291076284772e-03);  // ln2^4/4!
    p = __builtin_fma(p, r, 5.5504108664821580e-02);  // ln2^3/3!
    p = __builtin_fma(p, r, 2.4022650695910071e-01);  // ln2^2/2!
    p = __builtin_fma(p, r, 6.9314718055994531e-01);  // ln2
    p = __builtin_fma(p, r, 1.0);
    int ni = (int)n;
    long long bits = ((long long)(ni + 1023)) << 52;
    return p * __longlong_as_double(bits);
}

__global__ void __launch_bounds__(256)
histcal_kernel(const float* __restrict__ logits,
               const float* __restrict__ val_freqs,
               float* __restrict__ out)
{
    __shared__ float svf[NCLS * NBINS];
    for (int t = threadIdx.x; t < NCLS * NBINS; t += 256)
        svf[t] = val_freqs[t];
    __syncthreads();

    unsigned i  = blockIdx.x * 256u + threadIdx.x;
    unsigned b  = i >> 18;            // / HW
    unsigned hw = i & (HW - 1);
    size_t base = (size_t)b * ((size_t)NCLS * HW) + hw;
    const float* lp = logits + base;
    float*       op = out + base;

    // Load the 19 class logits (coalesced plane loads).
    float x[NCLS];
    #pragma unroll
    for (int c = 0; c < NCLS; ++c)
        x[c] = lp[(size_t)c * HW];

    // ---- f32 fast path: exp + sum ----
    float sf = 0.f;
    #pragma unroll
    for (int c = 0; c < NCLS; ++c)
        sf += __expf(x[c]);
    float scf = 15.f / sf;

    // Bin in f32; flag any element too close to a bin boundary.
    int bins[NCLS];
    bool risky = false;
    #pragma unroll
    for (int c = 0; c < NCLS; ++c) {
        float p15 = __expf(x[c]) * scf;            // compiler CSEs the exps
        risky |= fabsf(p15 - rintf(p15)) < EPS;
        int bi = (int)p15;                         // >=0, trunc == floor
        bins[c] = bi > NBINS - 1 ? NBINS - 1 : bi;
    }

    // ---- f64 fallback for boundary-adjacent lanes (exec-masked, usually
    // skipped entirely via s_cbranch_execz) ----
    if (__builtin_expect(risky, 0)) {
        double s = 0.0;
        #pragma unroll
        for (int c = 0; c < NCLS; ++c)
            s += dexp_fast((double)x[c]);
        double sc = 15.0 / s;
        #pragma unroll
        for (int c = 0; c < NCLS; ++c) {
            int bi = (int)(dexp_fast((double)x[c]) * sc);
            bins[c] = bi > NBINS - 1 ? NBINS - 1 : bi;
        }
    }

    // Gather + class-sum + normalize.
    float cal[NCLS];
    float t = 0.f;
    #pragma unroll
    for (int c = 0; c < NCLS; ++c) {
        float v = svf[c * NBINS + bins[c]];
        cal[c] = v;
        t += v;
    }
    if (t == 0.f) t = 1.f;
    float inv = 1.f / t;

    // Streaming write-out.
    #pragma unroll
    for (int c = 0; c < NCLS; ++c)
        __builtin_nontemporal_store(cal[c] * inv, op + (size_t)c * HW);
}

extern "C" void kernel_launch(void* const* d_in, const int* in_sizes, int n_in,
                              void* d_out, int out_size, void* d_ws, size_t ws_size,
                              hipStream_t stream) {
    const float* logits    = (const float*)d_in[0];   // [8,19,512,512] f32
    const float* val_freqs = (const float*)d_in[1];   // [19,15] f32
    float* out = (float*)d_out;                       // [8,19,512,512] f32
    histcal_kernel<<<dim3(NPIX / 256), dim3(256), 0, stream>>>(logits, val_freqs, out);
}